// Round 8
// baseline (143.584 us; speedup 1.0000x reference)
//
#include <hip/hip_runtime.h>

#define BB   256
#define NIMG 49
#define NGPS 32
#define DIM  256
#define MPAD 64

typedef __attribute__((ext_vector_type(8))) __bf16 bf16x8;
typedef __attribute__((ext_vector_type(4))) float  f32x4;
typedef __attribute__((ext_vector_type(4))) unsigned short u16x4;

__device__ inline unsigned short f2bf(float f) {
  unsigned int u = __float_as_uint(f);
  u += 0x7fff + ((u >> 16) & 1);   // round-to-nearest-even
  return (unsigned short)(u >> 16);
}

// DPP cross-lane reduce helpers (VALU pipe, no DS traffic).
template<int CTRL>
__device__ inline float dppmax(float v) {
  float o = __int_as_float(__builtin_amdgcn_update_dpp(0, __float_as_int(v), CTRL, 0xF, 0xF, true));
  return fmaxf(v, o);
}
template<int CTRL>
__device__ inline float dppadd(float v) {
  float o = __int_as_float(__builtin_amdgcn_update_dpp(0, __float_as_int(v), CTRL, 0xF, 0xF, true));
  return v + o;
}
__device__ inline float max16(float v) {   // max across the 16 lanes of a DPP row
  v = dppmax<0xB1>(v); v = dppmax<0x4E>(v); v = dppmax<0x141>(v); v = dppmax<0x140>(v);
  return v;
}
__device__ inline float sum16(float v) {   // sum across the 16 lanes of a DPP row
  v = dppadd<0xB1>(v); v = dppadd<0x4E>(v); v = dppadd<0x141>(v); v = dppadd<0x140>(v);
  return v;
}

// ---------------- kernel 1: L2-normalize + cast to bf16 (img padded to 64 rows/b) ----
__global__ __launch_bounds__(256) void norm_kernel(
    const float* __restrict__ img, const float* __restrict__ gps,
    unsigned short* __restrict__ imgN, unsigned short* __restrict__ gpsN)
{
  int w    = (blockIdx.x * 256 + threadIdx.x) >> 6;  // one wave per row
  int lane = threadIdx.x & 63;
  const float* src;
  unsigned short* dst;
  if (w < BB * MPAD) {
    int b = w >> 6, n = w & 63;
    dst = imgN + (size_t)w * DIM;
    if (n >= NIMG) {                                  // zero padding rows
      u16x4 z = {0, 0, 0, 0};
      *reinterpret_cast<u16x4*>(dst + lane * 4) = z;
      return;
    }
    src = img + ((size_t)b * NIMG + n) * DIM;
  } else {
    int t = w - BB * MPAD;
    dst = gpsN + (size_t)t * DIM;
    src = gps + (size_t)t * DIM;
  }
  f32x4 x = *reinterpret_cast<const f32x4*>(src + lane * 4);
  float ss = x[0]*x[0] + x[1]*x[1] + x[2]*x[2] + x[3]*x[3];
  #pragma unroll
  for (int d = 1; d < 64; d <<= 1) ss += __shfl_xor(ss, d);
  float inv = 1.0f / fmaxf(sqrtf(ss), 1e-12f);
  u16x4 o;
  o[0] = f2bf(x[0]*inv); o[1] = f2bf(x[1]*inv);
  o[2] = f2bf(x[2]*inv); o[3] = f2bf(x[3]*inv);
  *reinterpret_cast<u16x4*>(dst + lane * 4) = o;
}

// ---------------- kernel 2: all-pairs MFMA + fused max/mean reductions --------------
// grid: 2048 blocks = 256 b * 8 g-chunks; 4 waves/block, each wave owns 8 g's,
// processed TWO at a time: each A-frag ds_read feeds 4 MFMAs (r7 post-mortem:
// LDS pipe shared by 4 SIMDs was the co-binding pipe; 2-g halves DS+L2 traffic).
// A (img[b], 64x256 bf16 = 32KB) staged once in LDS, XOR-swizzled.
// TRANSPOSED mfma: gps frag = A-operand, img frag = B-operand -> D = S^T.
// REGISTER-PRESSURE CONTROL (r3/r5/r6/r7 lessons): kc loop `#pragma unroll 2`
// bounds in-flight loads; NO prefetch arrays (r5 blowup); named pointers only;
// (256,3) cap 170 -- lean body ~150 combined -> no spill, 3 waves/SIMD.
__global__ __launch_bounds__(256, 3) void pair_kernel(
    const unsigned short* __restrict__ imgN, const unsigned short* __restrict__ gpsN,
    float* __restrict__ i2g, float* __restrict__ g2i)
{
  int tid  = threadIdx.x;
  int wv   = tid >> 6;
  int lane = tid & 63;
  int c    = lane & 15, grp = lane >> 4;
  int b    = blockIdx.x >> 3, gc = blockIdx.x & 7;

  __shared__ unsigned short As[MPAD * DIM];   // 32 KB

  // ---- stage A: lane = row, each wave writes 8 of 32 16B-slots per row ----
  {
    const unsigned short* src = imgN + ((size_t)(b * MPAD + lane)) * DIM;
    unsigned int rb = lane * 512;             // row byte base (512 B/row)
    unsigned int sw = (lane & 7) << 4;        // XOR swizzle for this row
    #pragma unroll
    for (int i = 0; i < 8; ++i) {
      int s = wv * 8 + i;                     // 16B slot index 0..31
      bf16x8 v = *reinterpret_cast<const bf16x8*>(src + s * 8);
      *reinterpret_cast<bf16x8*>(reinterpret_cast<char*>(As) + ((rb + s * 16) ^ sw)) = v;
    }
  }
  __syncthreads();

  const char* Ab = reinterpret_cast<const char*>(As);
  unsigned int swr   = (c & 7) << 4;          // read-side swizzle
  unsigned int abase = c * 512;               // + hf*8192 + ((grp*16 + kc*64)^swr)

  int gfirst = gc * 32 + wv * 8;
  // named gps fragment pointers (g in {0,1}, mt in {0,1}); kc offset = kc*64 B (imm)
  const unsigned short* pg00 = gpsN + ((size_t)gfirst * NGPS + c) * DIM + grp * 8;
  const unsigned short* pg01 = pg00 + 4096;           // mt=1 (+16 rows)
  const unsigned short* pg10 = pg00 + NGPS * DIM;     // g+1
  const unsigned short* pg11 = pg10 + 4096;

  #pragma unroll 1
  for (int st = 0; st < 4; ++st) {
    f32x4 acc[2][2][4];                        // [g][mt (gps rows)][hf (img cols)]
    #pragma unroll
    for (int g = 0; g < 2; ++g)
      #pragma unroll
      for (int mt = 0; mt < 2; ++mt)
        #pragma unroll
        for (int hf = 0; hf < 4; ++hf)
          acc[g][mt][hf] = (f32x4){0.f, 0.f, 0.f, 0.f};

    #pragma unroll 2
    for (int kc = 0; kc < 8; ++kc) {
      bf16x8 q00 = *reinterpret_cast<const bf16x8*>(pg00 + kc * 32);
      bf16x8 q01 = *reinterpret_cast<const bf16x8*>(pg01 + kc * 32);
      bf16x8 q10 = *reinterpret_cast<const bf16x8*>(pg10 + kc * 32);
      bf16x8 q11 = *reinterpret_cast<const bf16x8*>(pg11 + kc * 32);
      unsigned int off = ((unsigned)(grp * 16 + kc * 64)) ^ swr;
      const char* ab = Ab + abase + off;
      bf16x8 a0 = *reinterpret_cast<const bf16x8*>(ab);
      bf16x8 a1 = *reinterpret_cast<const bf16x8*>(ab + 8192);
      bf16x8 a2 = *reinterpret_cast<const bf16x8*>(ab + 16384);
      bf16x8 a3 = *reinterpret_cast<const bf16x8*>(ab + 24576);
      acc[0][0][0] = __builtin_amdgcn_mfma_f32_16x16x32_bf16(q00, a0, acc[0][0][0], 0, 0, 0);
      acc[0][0][1] = __builtin_amdgcn_mfma_f32_16x16x32_bf16(q00, a1, acc[0][0][1], 0, 0, 0);
      acc[0][0][2] = __builtin_amdgcn_mfma_f32_16x16x32_bf16(q00, a2, acc[0][0][2], 0, 0, 0);
      acc[0][0][3] = __builtin_amdgcn_mfma_f32_16x16x32_bf16(q00, a3, acc[0][0][3], 0, 0, 0);
      acc[0][1][0] = __builtin_amdgcn_mfma_f32_16x16x32_bf16(q01, a0, acc[0][1][0], 0, 0, 0);
      acc[0][1][1] = __builtin_amdgcn_mfma_f32_16x16x32_bf16(q01, a1, acc[0][1][1], 0, 0, 0);
      acc[0][1][2] = __builtin_amdgcn_mfma_f32_16x16x32_bf16(q01, a2, acc[0][1][2], 0, 0, 0);
      acc[0][1][3] = __builtin_amdgcn_mfma_f32_16x16x32_bf16(q01, a3, acc[0][1][3], 0, 0, 0);
      acc[1][0][0] = __builtin_amdgcn_mfma_f32_16x16x32_bf16(q10, a0, acc[1][0][0], 0, 0, 0);
      acc[1][0][1] = __builtin_amdgcn_mfma_f32_16x16x32_bf16(q10, a1, acc[1][0][1], 0, 0, 0);
      acc[1][0][2] = __builtin_amdgcn_mfma_f32_16x16x32_bf16(q10, a2, acc[1][0][2], 0, 0, 0);
      acc[1][0][3] = __builtin_amdgcn_mfma_f32_16x16x32_bf16(q10, a3, acc[1][0][3], 0, 0, 0);
      acc[1][1][0] = __builtin_amdgcn_mfma_f32_16x16x32_bf16(q11, a0, acc[1][1][0], 0, 0, 0);
      acc[1][1][1] = __builtin_amdgcn_mfma_f32_16x16x32_bf16(q11, a1, acc[1][1][1], 0, 0, 0);
      acc[1][1][2] = __builtin_amdgcn_mfma_f32_16x16x32_bf16(q11, a2, acc[1][1][2], 0, 0, 0);
      acc[1][1][3] = __builtin_amdgcn_mfma_f32_16x16x32_bf16(q11, a3, acc[1][1][3], 0, 0, 0);
    }

    // ---- epilogue per g: D = S^T, row m = mt*16+grp*4+r (gps), col n = hf*16+c ----
    #pragma unroll
    for (int g = 0; g < 2; ++g) {
      // i2g: mean over n<49 of (max over m). max over m: in-lane (mt,r) + xor16/32.
      float vmax[4];
      #pragma unroll
      for (int hf = 0; hf < 4; ++hf) {
        float m0 = fmaxf(fmaxf(acc[g][0][hf][0], acc[g][0][hf][1]),
                         fmaxf(acc[g][0][hf][2], acc[g][0][hf][3]));
        float m1 = fmaxf(fmaxf(acc[g][1][hf][0], acc[g][1][hf][1]),
                         fmaxf(acc[g][1][hf][2], acc[g][1][hf][3]));
        float vm = fmaxf(m0, m1);
        vm = fmaxf(vm, __shfl_xor(vm, 16));
        vm = fmaxf(vm, __shfl_xor(vm, 32));
        vmax[hf] = vm;
      }
      // valid n: hf<3 all 16 c's; hf==3 only c==0 (n=48)
      float s = vmax[0] + vmax[1] + vmax[2] + ((c == 0) ? vmax[3] : 0.0f);
      s = sum16(s);                            // sum over c -> sum over n<49

      // g2i: mean over 32 m of (max over n<49). in-lane over hf (mask hf3), max16
      // over c, then sum over (mt,r) in-lane + xor16/32 over grp.
      float t = 0.f;
      #pragma unroll
      for (int mt = 0; mt < 2; ++mt)
        #pragma unroll
        for (int r = 0; r < 4; ++r) {
          float h3 = (c == 0) ? acc[g][mt][3][r] : -1.0e30f;
          float hm = fmaxf(fmaxf(acc[g][mt][0][r], acc[g][mt][1][r]),
                           fmaxf(acc[g][mt][2][r], h3));
          hm = max16(hm);
          t += hm;
        }
      t += __shfl_xor(t, 16);
      t += __shfl_xor(t, 32);

      if (lane == 0) {
        int gg = gfirst + st * 2 + g;
        i2g[b * 256 + gg] = s * (1.0f / NIMG);
        g2i[gg * 256 + b] = t * (1.0f / NGPS);
      }
    }
    pg00 += 2 * NGPS * DIM;                    // advance 2 g's
    pg01 += 2 * NGPS * DIM;
    pg10 += 2 * NGPS * DIM;
    pg11 += 2 * NGPS * DIM;
  }
}

// ---------------- kernel 3: per-row CE partials -------------------------------------
__global__ __launch_bounds__(256) void ce_kernel(
    const float* __restrict__ i2g, const float* __restrict__ g2i,
    const float* __restrict__ lsp, float* __restrict__ partial)
{
  int b = blockIdx.x, t = threadIdx.x, lane = t & 63, wv = t >> 6;
  float s = fminf(expf(lsp[0]), 100.0f);
  float v1 = s * i2g[b * 256 + t];
  float v2 = s * g2i[b * 256 + t];

  float m1 = v1, m2 = v2;
  #pragma unroll
  for (int d = 1; d < 64; d <<= 1) {
    m1 = fmaxf(m1, __shfl_xor(m1, d));
    m2 = fmaxf(m2, __shfl_xor(m2, d));
  }
  __shared__ float sm[2][4];
  if (lane == 0) { sm[0][wv] = m1; sm[1][wv] = m2; }
  __syncthreads();
  m1 = fmaxf(fmaxf(sm[0][0], sm[0][1]), fmaxf(sm[0][2], sm[0][3]));
  m2 = fmaxf(fmaxf(sm[1][0], sm[1][1]), fmaxf(sm[1][2], sm[1][3]));

  float e1 = expf(v1 - m1), e2 = expf(v2 - m2);
  #pragma unroll
  for (int d = 1; d < 64; d <<= 1) {
    e1 += __shfl_xor(e1, d);
    e2 += __shfl_xor(e2, d);
  }
  __shared__ float se[2][4];
  if (lane == 0) { se[0][wv] = e1; se[1][wv] = e2; }
  __syncthreads();
  if (t == 0) {
    float S1 = se[0][0] + se[0][1] + se[0][2] + se[0][3];
    float S2 = se[1][0] + se[1][1] + se[1][2] + se[1][3];
    float lse1 = m1 + logf(S1);
    float lse2 = m2 + logf(S2);
    partial[b] = (lse1 - s * i2g[b * 257]) + (lse2 - s * g2i[b * 257]);
  }
}

// ---------------- kernel 4: final scalar --------------------------------------------
__global__ __launch_bounds__(256) void finish_kernel(
    const float* __restrict__ partial, float* __restrict__ out)
{
  int t = threadIdx.x, lane = t & 63, wv = t >> 6;
  float v = partial[t];
  #pragma unroll
  for (int d = 1; d < 64; d <<= 1) v += __shfl_xor(v, d);
  __shared__ float sp[4];
  if (lane == 0) sp[wv] = v;
  __syncthreads();
  if (t == 0) out[0] = (sp[0] + sp[1] + sp[2] + sp[3]) * (1.0f / 512.0f);
}

extern "C" void kernel_launch(void* const* d_in, const int* in_sizes, int n_in,
                              void* d_out, int out_size, void* d_ws, size_t ws_size,
                              hipStream_t stream)
{
  const float* img = (const float*)d_in[0];
  const float* gps = (const float*)d_in[1];
  const float* lsp = (const float*)d_in[2];
  float* out = (float*)d_out;
  char* ws = (char*)d_ws;

  unsigned short* imgN = (unsigned short*)(ws);              //  8,388,608 B
  unsigned short* gpsN = (unsigned short*)(ws + 8388608);    //  4,194,304 B
  float* i2g     = (float*)(ws + 12582912);                  //    262,144 B
  float* g2i     = (float*)(ws + 12845056);                  //    262,144 B
  float* partial = (float*)(ws + 13107200);                  //      1,024 B

  norm_kernel<<<6144, 256, 0, stream>>>(img, gps, imgN, gpsN);
  pair_kernel<<<2048, 256, 0, stream>>>(imgN, gpsN, i2g, g2i);
  ce_kernel<<<256, 256, 0, stream>>>(i2g, g2i, lsp, partial);
  finish_kernel<<<1, 256, 0, stream>>>(partial, out);
}

// Round 9
// 90.070 us; speedup vs baseline: 1.5941x; 1.5941x over previous
//
#include <hip/hip_runtime.h>

#define BB   256
#define NIMG 49
#define NGPS 32
#define DIM  256
#define MPAD 64

typedef __attribute__((ext_vector_type(8))) __bf16 bf16x8;
typedef __attribute__((ext_vector_type(4))) float  f32x4;
typedef __attribute__((ext_vector_type(4))) unsigned int u32x4;

__device__ inline unsigned short f2bf(float f) {
  unsigned int u = __float_as_uint(f);
  u += 0x7fff + ((u >> 16) & 1);   // round-to-nearest-even
  return (unsigned short)(u >> 16);
}

// DPP cross-lane reduce helpers (VALU pipe, no DS traffic).
template<int CTRL>
__device__ inline float dppmax(float v) {
  float o = __int_as_float(__builtin_amdgcn_update_dpp(0, __float_as_int(v), CTRL, 0xF, 0xF, true));
  return fmaxf(v, o);
}
template<int CTRL>
__device__ inline float dppadd(float v) {
  float o = __int_as_float(__builtin_amdgcn_update_dpp(0, __float_as_int(v), CTRL, 0xF, 0xF, true));
  return v + o;
}
__device__ inline float max16(float v) {   // max across the 16 lanes of a DPP row
  v = dppmax<0xB1>(v); v = dppmax<0x4E>(v); v = dppmax<0x141>(v); v = dppmax<0x140>(v);
  return v;
}
__device__ inline float sum16(float v) {   // sum across the 16 lanes of a DPP row
  v = dppadd<0xB1>(v); v = dppadd<0x4E>(v); v = dppadd<0x141>(v); v = dppadd<0x140>(v);
  return v;
}

// ---------------- kernel 1: L2-normalize + cast to bf16, FRAGMENT-CONTIGUOUS layout --
// Workspace layouts are pre-swizzled into MFMA-fragment order so every hot-loop
// global load in pair_kernel is `lane i reads base + i*16B` (one contiguous 1KB
// wave transaction). r8's row-major layouts made every operand load 16 scattered
// 64B segments (row stride 512B) -- the surviving theory for the ~500TF plateau.
//   imgS[b][chunk s=0..31][row 0..63][8 bf16]  (b stride 16384 elem)
//   gpsS[g][mt][kc][grp*16+c][8 bf16]          (g stride 8192 elem)
__global__ __launch_bounds__(256) void norm_kernel(
    const float* __restrict__ img, const float* __restrict__ gps,
    unsigned short* __restrict__ imgS, unsigned short* __restrict__ gpsS)
{
  int w    = (blockIdx.x * 256 + threadIdx.x) >> 6;  // one wave per row
  int lane = threadIdx.x & 63;

  f32x4 x = (f32x4){0.f, 0.f, 0.f, 0.f};
  bool isimg; int b = 0, n = 0, g = 0, m = 0;
  if (w < BB * MPAD) {
    isimg = true; b = w >> 6; n = w & 63;
    if (n < NIMG)
      x = *reinterpret_cast<const f32x4*>(img + ((size_t)b * NIMG + n) * DIM + lane * 4);
  } else {
    isimg = false; int t = w - BB * MPAD; g = t >> 5; m = t & 31;
    x = *reinterpret_cast<const f32x4*>(gps + (size_t)t * DIM + lane * 4);
  }

  float ss = x[0]*x[0] + x[1]*x[1] + x[2]*x[2] + x[3]*x[3];
  #pragma unroll
  for (int d = 1; d < 64; d <<= 1) ss += __shfl_xor(ss, d);
  float inv = (ss > 0.f) ? (1.0f / fmaxf(sqrtf(ss), 1e-12f)) : 0.f;

  // pack this lane's 4 bf16 (elems lane*4 .. lane*4+3) into two u32
  unsigned int w01 = (unsigned)f2bf(x[0]*inv) | ((unsigned)f2bf(x[1]*inv) << 16);
  unsigned int w23 = (unsigned)f2bf(x[2]*inv) | ((unsigned)f2bf(x[3]*inv) << 16);

  // lane L (<32) gathers chunk L = row elems [8L, 8L+8) from lanes 2L, 2L+1
  int L = lane;
  unsigned int a0 = __shfl(w01, 2 * L);
  unsigned int a1 = __shfl(w23, 2 * L);
  unsigned int a2 = __shfl(w01, 2 * L + 1);
  unsigned int a3 = __shfl(w23, 2 * L + 1);
  if (L < 32) {
    u32x4 v = {a0, a1, a2, a3};
    unsigned short* dst;
    if (isimg) {
      dst = imgS + (size_t)b * 16384 + L * 512 + n * 8;          // [b][s=L][row n]
    } else {
      int mt = m >> 4, c = m & 15, kc = L >> 2, grp = L & 3;
      dst = gpsS + (size_t)g * 8192 + mt * 4096 + kc * 512 + (grp * 16 + c) * 8;
    }
    *reinterpret_cast<u32x4*>(dst) = v;
  }
}

// ---------------- kernel 2: all-pairs MFMA + fused max/mean reductions --------------
// grid: 2048 blocks = 256 b * 8 g-chunks; 4 waves/block, each wave owns 8 g's,
// processed TWO at a time (each A-frag ds_read feeds 4 MFMAs).
// A (img[b], 64x256 bf16 = 32KB) staged once in LDS, XOR-swizzled; staging reads
// are NONTEMPORAL (stream-once) so they don't evict gps from L1/L2.
// All global loads are contiguous 1KB wave transactions (fragment-major layout).
// TRANSPOSED mfma: gps frag = A-operand, img frag = B-operand -> D = S^T.
// REGISTER-PRESSURE CONTROL (r3/r5/r6/r7): kc loop `#pragma unroll 2`; no
// prefetch arrays; named pointers; (256,3) cap 170 -> no spill, 3 waves/SIMD.
__global__ __launch_bounds__(256, 3) void pair_kernel(
    const unsigned short* __restrict__ imgS, const unsigned short* __restrict__ gpsS,
    float* __restrict__ i2g, float* __restrict__ g2i)
{
  int tid  = threadIdx.x;
  int wv   = tid >> 6;
  int lane = tid & 63;
  int c    = lane & 15, grp = lane >> 4;
  int b    = blockIdx.x >> 3, gc = blockIdx.x & 7;

  __shared__ unsigned short As[MPAD * DIM];   // 32 KB

  // ---- stage A: chunk-major source, contiguous 1KB loads; LDS layout unchanged ----
  {
    const unsigned short* src = imgS + (size_t)b * 16384 + lane * 8;
    #pragma unroll
    for (int i = 0; i < 8; ++i) {
      int s = wv * 8 + i;                     // 16B chunk index 0..31
      // imgS[b][s][row=?]: we need row `lane`'s chunk s at LDS row `lane`.
      // src + s*512 + lane*8 would be row-lane... careful: layout is
      // [s][row][8]: elem = s*512 + row*8. This wave-lane loads row=lane:
      bf16x8 v = __builtin_nontemporal_load(
          reinterpret_cast<const bf16x8*>(src + s * 512));
      unsigned int rb = lane * 512;           // LDS row byte base
      unsigned int sw = (lane & 7) << 4;      // XOR swizzle
      *reinterpret_cast<bf16x8*>(reinterpret_cast<char*>(As) + ((rb + s * 16) ^ sw)) = v;
    }
  }
  __syncthreads();

  const char* Ab = reinterpret_cast<const char*>(As);
  unsigned int swr   = (c & 7) << 4;          // read-side swizzle
  unsigned int abase = c * 512;               // + hf*8192 + ((grp*16 + kc*64)^swr)

  int gfirst = gc * 32 + wv * 8;
  // fragment-major gps: base + g*8192 + mt*4096 + kc*512 + lane*8  (all elems)
  const unsigned short* pg00 = gpsS + (size_t)gfirst * 8192 + lane * 8;
  const unsigned short* pg01 = pg00 + 4096;           // mt=1
  const unsigned short* pg10 = pg00 + 8192;           // g+1
  const unsigned short* pg11 = pg10 + 4096;

  #pragma unroll 1
  for (int st = 0; st < 4; ++st) {
    f32x4 acc[2][2][4];                        // [g][mt (gps rows)][hf (img cols)]
    #pragma unroll
    for (int g = 0; g < 2; ++g)
      #pragma unroll
      for (int mt = 0; mt < 2; ++mt)
        #pragma unroll
        for (int hf = 0; hf < 4; ++hf)
          acc[g][mt][hf] = (f32x4){0.f, 0.f, 0.f, 0.f};

    #pragma unroll 2
    for (int kc = 0; kc < 8; ++kc) {
      bf16x8 q00 = *reinterpret_cast<const bf16x8*>(pg00 + kc * 512);
      bf16x8 q01 = *reinterpret_cast<const bf16x8*>(pg01 + kc * 512);
      bf16x8 q10 = *reinterpret_cast<const bf16x8*>(pg10 + kc * 512);
      bf16x8 q11 = *reinterpret_cast<const bf16x8*>(pg11 + kc * 512);
      unsigned int off = ((unsigned)(grp * 16 + kc * 64)) ^ swr;
      const char* ab = Ab + abase + off;
      bf16x8 a0 = *reinterpret_cast<const bf16x8*>(ab);
      bf16x8 a1 = *reinterpret_cast<const bf16x8*>(ab + 8192);
      bf16x8 a2 = *reinterpret_cast<const bf16x8*>(ab + 16384);
      bf16x8 a3 = *reinterpret_cast<const bf16x8*>(ab + 24576);
      acc[0][0][0] = __builtin_amdgcn_mfma_f32_16x16x32_bf16(q00, a0, acc[0][0][0], 0, 0, 0);
      acc[0][0][1] = __builtin_amdgcn_mfma_f32_16x16x32_bf16(q00, a1, acc[0][0][1], 0, 0, 0);
      acc[0][0][2] = __builtin_amdgcn_mfma_f32_16x16x32_bf16(q00, a2, acc[0][0][2], 0, 0, 0);
      acc[0][0][3] = __builtin_amdgcn_mfma_f32_16x16x32_bf16(q00, a3, acc[0][0][3], 0, 0, 0);
      acc[0][1][0] = __builtin_amdgcn_mfma_f32_16x16x32_bf16(q01, a0, acc[0][1][0], 0, 0, 0);
      acc[0][1][1] = __builtin_amdgcn_mfma_f32_16x16x32_bf16(q01, a1, acc[0][1][1], 0, 0, 0);
      acc[0][1][2] = __builtin_amdgcn_mfma_f32_16x16x32_bf16(q01, a2, acc[0][1][2], 0, 0, 0);
      acc[0][1][3] = __builtin_amdgcn_mfma_f32_16x16x32_bf16(q01, a3, acc[0][1][3], 0, 0, 0);
      acc[1][0][0] = __builtin_amdgcn_mfma_f32_16x16x32_bf16(q10, a0, acc[1][0][0], 0, 0, 0);
      acc[1][0][1] = __builtin_amdgcn_mfma_f32_16x16x32_bf16(q10, a1, acc[1][0][1], 0, 0, 0);
      acc[1][0][2] = __builtin_amdgcn_mfma_f32_16x16x32_bf16(q10, a2, acc[1][0][2], 0, 0, 0);
      acc[1][0][3] = __builtin_amdgcn_mfma_f32_16x16x32_bf16(q10, a3, acc[1][0][3], 0, 0, 0);
      acc[1][1][0] = __builtin_amdgcn_mfma_f32_16x16x32_bf16(q11, a0, acc[1][1][0], 0, 0, 0);
      acc[1][1][1] = __builtin_amdgcn_mfma_f32_16x16x32_bf16(q11, a1, acc[1][1][1], 0, 0, 0);
      acc[1][1][2] = __builtin_amdgcn_mfma_f32_16x16x32_bf16(q11, a2, acc[1][1][2], 0, 0, 0);
      acc[1][1][3] = __builtin_amdgcn_mfma_f32_16x16x32_bf16(q11, a3, acc[1][1][3], 0, 0, 0);
    }

    // ---- epilogue per g: D = S^T, row m = mt*16+grp*4+r (gps), col n = hf*16+c ----
    #pragma unroll
    for (int g = 0; g < 2; ++g) {
      // i2g: mean over n<49 of (max over m). max over m: in-lane (mt,r) + xor16/32.
      float vmax[4];
      #pragma unroll
      for (int hf = 0; hf < 4; ++hf) {
        float m0 = fmaxf(fmaxf(acc[g][0][hf][0], acc[g][0][hf][1]),
                         fmaxf(acc[g][0][hf][2], acc[g][0][hf][3]));
        float m1 = fmaxf(fmaxf(acc[g][1][hf][0], acc[g][1][hf][1]),
                         fmaxf(acc[g][1][hf][2], acc[g][1][hf][3]));
        float vm = fmaxf(m0, m1);
        vm = fmaxf(vm, __shfl_xor(vm, 16));
        vm = fmaxf(vm, __shfl_xor(vm, 32));
        vmax[hf] = vm;
      }
      // valid n: hf<3 all 16 c's; hf==3 only c==0 (n=48)
      float s = vmax[0] + vmax[1] + vmax[2] + ((c == 0) ? vmax[3] : 0.0f);
      s = sum16(s);                            // sum over c -> sum over n<49

      // g2i: mean over 32 m of (max over n<49). in-lane over hf (mask hf3), max16
      // over c, then sum over (mt,r) in-lane + xor16/32 over grp.
      float t = 0.f;
      #pragma unroll
      for (int mt = 0; mt < 2; ++mt)
        #pragma unroll
        for (int r = 0; r < 4; ++r) {
          float h3 = (c == 0) ? acc[g][mt][3][r] : -1.0e30f;
          float hm = fmaxf(fmaxf(acc[g][mt][0][r], acc[g][mt][1][r]),
                           fmaxf(acc[g][mt][2][r], h3));
          hm = max16(hm);
          t += hm;
        }
      t += __shfl_xor(t, 16);
      t += __shfl_xor(t, 32);

      if (lane == 0) {
        int gg = gfirst + st * 2 + g;
        i2g[b * 256 + gg] = s * (1.0f / NIMG);
        g2i[gg * 256 + b] = t * (1.0f / NGPS);
      }
    }
    pg00 += 16384;                             // advance 2 g tiles (2*8192 elems)
    pg01 += 16384;
    pg10 += 16384;
    pg11 += 16384;
  }
}

// ---------------- kernel 3: per-row CE partials -------------------------------------
__global__ __launch_bounds__(256) void ce_kernel(
    const float* __restrict__ i2g, const float* __restrict__ g2i,
    const float* __restrict__ lsp, float* __restrict__ partial)
{
  int b = blockIdx.x, t = threadIdx.x, lane = t & 63, wv = t >> 6;
  float s = fminf(expf(lsp[0]), 100.0f);
  float v1 = s * i2g[b * 256 + t];
  float v2 = s * g2i[b * 256 + t];

  float m1 = v1, m2 = v2;
  #pragma unroll
  for (int d = 1; d < 64; d <<= 1) {
    m1 = fmaxf(m1, __shfl_xor(m1, d));
    m2 = fmaxf(m2, __shfl_xor(m2, d));
  }
  __shared__ float sm[2][4];
  if (lane == 0) { sm[0][wv] = m1; sm[1][wv] = m2; }
  __syncthreads();
  m1 = fmaxf(fmaxf(sm[0][0], sm[0][1]), fmaxf(sm[0][2], sm[0][3]));
  m2 = fmaxf(fmaxf(sm[1][0], sm[1][1]), fmaxf(sm[1][2], sm[1][3]));

  float e1 = expf(v1 - m1), e2 = expf(v2 - m2);
  #pragma unroll
  for (int d = 1; d < 64; d <<= 1) {
    e1 += __shfl_xor(e1, d);
    e2 += __shfl_xor(e2, d);
  }
  __shared__ float se[2][4];
  if (lane == 0) { se[0][wv] = e1; se[1][wv] = e2; }
  __syncthreads();
  if (t == 0) {
    float S1 = se[0][0] + se[0][1] + se[0][2] + se[0][3];
    float S2 = se[1][0] + se[1][1] + se[1][2] + se[1][3];
    float lse1 = m1 + logf(S1);
    float lse2 = m2 + logf(S2);
    partial[b] = (lse1 - s * i2g[b * 257]) + (lse2 - s * g2i[b * 257]);
  }
}

// ---------------- kernel 4: final scalar --------------------------------------------
__global__ __launch_bounds__(256) void finish_kernel(
    const float* __restrict__ partial, float* __restrict__ out)
{
  int t = threadIdx.x, lane = t & 63, wv = t >> 6;
  float v = partial[t];
  #pragma unroll
  for (int d = 1; d < 64; d <<= 1) v += __shfl_xor(v, d);
  __shared__ float sp[4];
  if (lane == 0) sp[wv] = v;
  __syncthreads();
  if (t == 0) out[0] = (sp[0] + sp[1] + sp[2] + sp[3]) * (1.0f / 512.0f);
}

extern "C" void kernel_launch(void* const* d_in, const int* in_sizes, int n_in,
                              void* d_out, int out_size, void* d_ws, size_t ws_size,
                              hipStream_t stream)
{
  const float* img = (const float*)d_in[0];
  const float* gps = (const float*)d_in[1];
  const float* lsp = (const float*)d_in[2];
  float* out = (float*)d_out;
  char* ws = (char*)d_ws;

  unsigned short* imgS = (unsigned short*)(ws);              //  8,388,608 B
  unsigned short* gpsS = (unsigned short*)(ws + 8388608);    //  4,194,304 B
  float* i2g     = (float*)(ws + 12582912);                  //    262,144 B
  float* g2i     = (float*)(ws + 12845056);                  //    262,144 B
  float* partial = (float*)(ws + 13107200);                  //      1,024 B

  norm_kernel<<<6144, 256, 0, stream>>>(img, gps, imgS, gpsS);
  pair_kernel<<<2048, 256, 0, stream>>>(imgS, gpsS, i2g, g2i);
  ce_kernel<<<256, 256, 0, stream>>>(i2g, g2i, lsp, partial);
  finish_kernel<<<1, 256, 0, stream>>>(partial, out);
}

// Round 10
// 87.085 us; speedup vs baseline: 1.6488x; 1.0343x over previous
//
#include <hip/hip_runtime.h>

#define BB   256
#define NIMG 49
#define NGPS 32
#define DIM  256
#define MPAD 64

typedef __attribute__((ext_vector_type(8))) __bf16 bf16x8;
typedef __attribute__((ext_vector_type(4))) float  f32x4;
typedef __attribute__((ext_vector_type(4))) unsigned int u32x4;

__device__ inline unsigned short f2bf(float f) {
  unsigned int u = __float_as_uint(f);
  u += 0x7fff + ((u >> 16) & 1);   // round-to-nearest-even
  return (unsigned short)(u >> 16);
}

// DPP cross-lane reduce helpers (VALU pipe, no DS traffic).
template<int CTRL>
__device__ inline float dppmax(float v) {
  float o = __int_as_float(__builtin_amdgcn_update_dpp(0, __float_as_int(v), CTRL, 0xF, 0xF, true));
  return fmaxf(v, o);
}
template<int CTRL>
__device__ inline float dppadd(float v) {
  float o = __int_as_float(__builtin_amdgcn_update_dpp(0, __float_as_int(v), CTRL, 0xF, 0xF, true));
  return v + o;
}
__device__ inline float max16(float v) {   // max across the 16 lanes of a DPP row
  v = dppmax<0xB1>(v); v = dppmax<0x4E>(v); v = dppmax<0x141>(v); v = dppmax<0x140>(v);
  return v;
}
__device__ inline float sum16(float v) {   // sum across the 16 lanes of a DPP row
  v = dppadd<0xB1>(v); v = dppadd<0x4E>(v); v = dppadd<0x141>(v); v = dppadd<0x140>(v);
  return v;
}

// ---------------- kernel 1: L2-normalize + cast to bf16, FRAGMENT-CONTIGUOUS layout --
// (r9 win: +44%. Every hot-loop global load is `lane i reads base + i*16B`.)
//   imgS[b][chunk s=0..31][row 0..63][8 bf16]  (b stride 16384 elem)
//   gpsS[g][mt][kc][grp*16+c][8 bf16]          (g stride 8192 elem)
__global__ __launch_bounds__(256) void norm_kernel(
    const float* __restrict__ img, const float* __restrict__ gps,
    unsigned short* __restrict__ imgS, unsigned short* __restrict__ gpsS)
{
  int w    = (blockIdx.x * 256 + threadIdx.x) >> 6;  // one wave per row
  int lane = threadIdx.x & 63;

  f32x4 x = (f32x4){0.f, 0.f, 0.f, 0.f};
  bool isimg; int b = 0, n = 0, g = 0, m = 0;
  if (w < BB * MPAD) {
    isimg = true; b = w >> 6; n = w & 63;
    if (n < NIMG)
      x = *reinterpret_cast<const f32x4*>(img + ((size_t)b * NIMG + n) * DIM + lane * 4);
  } else {
    isimg = false; int t = w - BB * MPAD; g = t >> 5; m = t & 31;
    x = *reinterpret_cast<const f32x4*>(gps + (size_t)t * DIM + lane * 4);
  }

  float ss = x[0]*x[0] + x[1]*x[1] + x[2]*x[2] + x[3]*x[3];
  #pragma unroll
  for (int d = 1; d < 64; d <<= 1) ss += __shfl_xor(ss, d);
  float inv = (ss > 0.f) ? (1.0f / fmaxf(sqrtf(ss), 1e-12f)) : 0.f;

  // pack this lane's 4 bf16 (elems lane*4 .. lane*4+3) into two u32
  unsigned int w01 = (unsigned)f2bf(x[0]*inv) | ((unsigned)f2bf(x[1]*inv) << 16);
  unsigned int w23 = (unsigned)f2bf(x[2]*inv) | ((unsigned)f2bf(x[3]*inv) << 16);

  // lane L (<32) gathers chunk L = row elems [8L, 8L+8) from lanes 2L, 2L+1
  int L = lane;
  unsigned int a0 = __shfl(w01, 2 * L);
  unsigned int a1 = __shfl(w23, 2 * L);
  unsigned int a2 = __shfl(w01, 2 * L + 1);
  unsigned int a3 = __shfl(w23, 2 * L + 1);
  if (L < 32) {
    u32x4 v = {a0, a1, a2, a3};
    unsigned short* dst;
    if (isimg) {
      dst = imgS + (size_t)b * 16384 + L * 512 + n * 8;          // [b][s=L][row n]
    } else {
      int mt = m >> 4, c = m & 15, kc = L >> 2, grp = L & 3;
      dst = gpsS + (size_t)g * 8192 + mt * 4096 + kc * 512 + (grp * 16 + c) * 8;
    }
    *reinterpret_cast<u32x4*>(dst) = v;
  }
}

// ---------------- kernel 2: all-pairs MFMA + fused max/mean reductions --------------
// grid: 2048 blocks = 256 b * 8 g-chunks; 4 waves/block, 2 g's per wave step.
// A (img[b], 64x256 bf16 = 32KB) staged once in LDS, XOR-swizzled (swizzle is
// conflict-minimal: b128 wave read = 8 lanes/bank-quad floor).
// TRANSPOSED mfma: gps frag = A-operand, img frag = B-operand -> D = S^T.
// OCCUPANCY PUSH (r9 post-mortem): measured combined regs = 60 VGPR + 64 AGPR
// = 124 <= 128 -> force __launch_bounds__(256,4); gps bases readfirstlane'd to
// SGPR (frees ~6 VGPR of pointer pairs). Spill guard: WRITE_SIZE must stay ~0.5MB.
// kc loop `#pragma unroll 2` is the liveness throttle (r7) -- do not full-unroll.
__global__ __launch_bounds__(256, 4) void pair_kernel(
    const unsigned short* __restrict__ imgS, const unsigned short* __restrict__ gpsS,
    float* __restrict__ i2g, float* __restrict__ g2i)
{
  int tid  = threadIdx.x;
  int wv   = tid >> 6;
  int lane = tid & 63;
  int c    = lane & 15, grp = lane >> 4;
  int b    = blockIdx.x >> 3, gc = blockIdx.x & 7;
  int wvu  = __builtin_amdgcn_readfirstlane(wv);   // wave-uniform -> SGPR

  __shared__ unsigned short As[MPAD * DIM];   // 32 KB

  // ---- stage A: chunk-major source, contiguous 1KB loads; XOR-swizzled LDS ----
  {
    const unsigned short* src = imgS + (size_t)b * 16384 + lane * 8;
    #pragma unroll
    for (int i = 0; i < 8; ++i) {
      int s = wvu * 8 + i;                    // 16B chunk index 0..31
      bf16x8 v = *reinterpret_cast<const bf16x8*>(src + s * 512);
      unsigned int rb = lane * 512;           // LDS row byte base
      unsigned int sw = (lane & 7) << 4;      // XOR swizzle
      *reinterpret_cast<bf16x8*>(reinterpret_cast<char*>(As) + ((rb + s * 16) ^ sw)) = v;
    }
  }
  __syncthreads();

  const char* Ab = reinterpret_cast<const char*>(As);
  unsigned int swr   = (c & 7) << 4;          // read-side swizzle
  unsigned int abase = c * 512;               // + hf*8192 + ((grp*16 + kc*64)^swr)

  // wave-uniform gps tile base (SGPR) + single per-lane element offset
  const unsigned short* gb = gpsS + ((size_t)(gc * 32 + wvu * 8)) * 8192;
  unsigned int lane8 = lane * 8;

  #pragma unroll 1
  for (int st = 0; st < 4; ++st) {
    f32x4 acc[2][2][4];                        // [g][mt (gps rows)][hf (img cols)]
    #pragma unroll
    for (int g = 0; g < 2; ++g)
      #pragma unroll
      for (int mt = 0; mt < 2; ++mt)
        #pragma unroll
        for (int hf = 0; hf < 4; ++hf)
          acc[g][mt][hf] = (f32x4){0.f, 0.f, 0.f, 0.f};

    #pragma unroll 2
    for (int kc = 0; kc < 8; ++kc) {
      const unsigned short* p = gb + kc * 512 + lane8;
      bf16x8 q00 = *reinterpret_cast<const bf16x8*>(p);
      bf16x8 q01 = *reinterpret_cast<const bf16x8*>(p + 4096);
      bf16x8 q10 = *reinterpret_cast<const bf16x8*>(p + 8192);
      bf16x8 q11 = *reinterpret_cast<const bf16x8*>(p + 12288);
      unsigned int off = ((unsigned)(grp * 16 + kc * 64)) ^ swr;
      const char* ab = Ab + abase + off;
      bf16x8 a0 = *reinterpret_cast<const bf16x8*>(ab);
      bf16x8 a1 = *reinterpret_cast<const bf16x8*>(ab + 8192);
      bf16x8 a2 = *reinterpret_cast<const bf16x8*>(ab + 16384);
      bf16x8 a3 = *reinterpret_cast<const bf16x8*>(ab + 24576);
      acc[0][0][0] = __builtin_amdgcn_mfma_f32_16x16x32_bf16(q00, a0, acc[0][0][0], 0, 0, 0);
      acc[0][0][1] = __builtin_amdgcn_mfma_f32_16x16x32_bf16(q00, a1, acc[0][0][1], 0, 0, 0);
      acc[0][0][2] = __builtin_amdgcn_mfma_f32_16x16x32_bf16(q00, a2, acc[0][0][2], 0, 0, 0);
      acc[0][0][3] = __builtin_amdgcn_mfma_f32_16x16x32_bf16(q00, a3, acc[0][0][3], 0, 0, 0);
      acc[0][1][0] = __builtin_amdgcn_mfma_f32_16x16x32_bf16(q01, a0, acc[0][1][0], 0, 0, 0);
      acc[0][1][1] = __builtin_amdgcn_mfma_f32_16x16x32_bf16(q01, a1, acc[0][1][1], 0, 0, 0);
      acc[0][1][2] = __builtin_amdgcn_mfma_f32_16x16x32_bf16(q01, a2, acc[0][1][2], 0, 0, 0);
      acc[0][1][3] = __builtin_amdgcn_mfma_f32_16x16x32_bf16(q01, a3, acc[0][1][3], 0, 0, 0);
      acc[1][0][0] = __builtin_amdgcn_mfma_f32_16x16x32_bf16(q10, a0, acc[1][0][0], 0, 0, 0);
      acc[1][0][1] = __builtin_amdgcn_mfma_f32_16x16x32_bf16(q10, a1, acc[1][0][1], 0, 0, 0);
      acc[1][0][2] = __builtin_amdgcn_mfma_f32_16x16x32_bf16(q10, a2, acc[1][0][2], 0, 0, 0);
      acc[1][0][3] = __builtin_amdgcn_mfma_f32_16x16x32_bf16(q10, a3, acc[1][0][3], 0, 0, 0);
      acc[1][1][0] = __builtin_amdgcn_mfma_f32_16x16x32_bf16(q11, a0, acc[1][1][0], 0, 0, 0);
      acc[1][1][1] = __builtin_amdgcn_mfma_f32_16x16x32_bf16(q11, a1, acc[1][1][1], 0, 0, 0);
      acc[1][1][2] = __builtin_amdgcn_mfma_f32_16x16x32_bf16(q11, a2, acc[1][1][2], 0, 0, 0);
      acc[1][1][3] = __builtin_amdgcn_mfma_f32_16x16x32_bf16(q11, a3, acc[1][1][3], 0, 0, 0);
    }

    // ---- epilogue per g: D = S^T, row m = mt*16+grp*4+r (gps), col n = hf*16+c ----
    #pragma unroll
    for (int g = 0; g < 2; ++g) {
      // i2g: mean over n<49 of (max over m). max over m: in-lane (mt,r) + xor16/32.
      float vmax[4];
      #pragma unroll
      for (int hf = 0; hf < 4; ++hf) {
        float m0 = fmaxf(fmaxf(acc[g][0][hf][0], acc[g][0][hf][1]),
                         fmaxf(acc[g][0][hf][2], acc[g][0][hf][3]));
        float m1 = fmaxf(fmaxf(acc[g][1][hf][0], acc[g][1][hf][1]),
                         fmaxf(acc[g][1][hf][2], acc[g][1][hf][3]));
        float vm = fmaxf(m0, m1);
        vm = fmaxf(vm, __shfl_xor(vm, 16));
        vm = fmaxf(vm, __shfl_xor(vm, 32));
        vmax[hf] = vm;
      }
      // valid n: hf<3 all 16 c's; hf==3 only c==0 (n=48)
      float s = vmax[0] + vmax[1] + vmax[2] + ((c == 0) ? vmax[3] : 0.0f);
      s = sum16(s);                            // sum over c -> sum over n<49

      // g2i: mean over 32 m of (max over n<49). in-lane over hf (mask hf3), max16
      // over c, then sum over (mt,r) in-lane + xor16/32 over grp.
      float t = 0.f;
      #pragma unroll
      for (int mt = 0; mt < 2; ++mt)
        #pragma unroll
        for (int r = 0; r < 4; ++r) {
          float h3 = (c == 0) ? acc[g][mt][3][r] : -1.0e30f;
          float hm = fmaxf(fmaxf(acc[g][mt][0][r], acc[g][mt][1][r]),
                           fmaxf(acc[g][mt][2][r], h3));
          hm = max16(hm);
          t += hm;
        }
      t += __shfl_xor(t, 16);
      t += __shfl_xor(t, 32);

      if (lane == 0) {
        int gg = gc * 32 + wvu * 8 + st * 2 + g;
        i2g[b * 256 + gg] = s * (1.0f / NIMG);
        g2i[gg * 256 + b] = t * (1.0f / NGPS);
      }
    }
    gb += 16384;                               // advance 2 g tiles (2*8192 elems)
  }
}

// ---------------- kernel 3: per-row CE partials -------------------------------------
__global__ __launch_bounds__(256) void ce_kernel(
    const float* __restrict__ i2g, const float* __restrict__ g2i,
    const float* __restrict__ lsp, float* __restrict__ partial)
{
  int b = blockIdx.x, t = threadIdx.x, lane = t & 63, wv = t >> 6;
  float s = fminf(expf(lsp[0]), 100.0f);
  float v1 = s * i2g[b * 256 + t];
  float v2 = s * g2i[b * 256 + t];

  float m1 = v1, m2 = v2;
  #pragma unroll
  for (int d = 1; d < 64; d <<= 1) {
    m1 = fmaxf(m1, __shfl_xor(m1, d));
    m2 = fmaxf(m2, __shfl_xor(m2, d));
  }
  __shared__ float sm[2][4];
  if (lane == 0) { sm[0][wv] = m1; sm[1][wv] = m2; }
  __syncthreads();
  m1 = fmaxf(fmaxf(sm[0][0], sm[0][1]), fmaxf(sm[0][2], sm[0][3]));
  m2 = fmaxf(fmaxf(sm[1][0], sm[1][1]), fmaxf(sm[1][2], sm[1][3]));

  float e1 = expf(v1 - m1), e2 = expf(v2 - m2);
  #pragma unroll
  for (int d = 1; d < 64; d <<= 1) {
    e1 += __shfl_xor(e1, d);
    e2 += __shfl_xor(e2, d);
  }
  __shared__ float se[2][4];
  if (lane == 0) { se[0][wv] = e1; se[1][wv] = e2; }
  __syncthreads();
  if (t == 0) {
    float S1 = se[0][0] + se[0][1] + se[0][2] + se[0][3];
    float S2 = se[1][0] + se[1][1] + se[1][2] + se[1][3];
    float lse1 = m1 + logf(S1);
    float lse2 = m2 + logf(S2);
    partial[b] = (lse1 - s * i2g[b * 257]) + (lse2 - s * g2i[b * 257]);
  }
}

// ---------------- kernel 4: final scalar --------------------------------------------
__global__ __launch_bounds__(256) void finish_kernel(
    const float* __restrict__ partial, float* __restrict__ out)
{
  int t = threadIdx.x, lane = t & 63, wv = t >> 6;
  float v = partial[t];
  #pragma unroll
  for (int d = 1; d < 64; d <<= 1) v += __shfl_xor(v, d);
  __shared__ float sp[4];
  if (lane == 0) sp[wv] = v;
  __syncthreads();
  if (t == 0) out[0] = (sp[0] + sp[1] + sp[2] + sp[3]) * (1.0f / 512.0f);
}

extern "C" void kernel_launch(void* const* d_in, const int* in_sizes, int n_in,
                              void* d_out, int out_size, void* d_ws, size_t ws_size,
                              hipStream_t stream)
{
  const float* img = (const float*)d_in[0];
  const float* gps = (const float*)d_in[1];
  const float* lsp = (const float*)d_in[2];
  float* out = (float*)d_out;
  char* ws = (char*)d_ws;

  unsigned short* imgS = (unsigned short*)(ws);              //  8,388,608 B
  unsigned short* gpsS = (unsigned short*)(ws + 8388608);    //  4,194,304 B
  float* i2g     = (float*)(ws + 12582912);                  //    262,144 B
  float* g2i     = (float*)(ws + 12845056);                  //    262,144 B
  float* partial = (float*)(ws + 13107200);                  //      1,024 B

  norm_kernel<<<6144, 256, 0, stream>>>(img, gps, imgS, gpsS);
  pair_kernel<<<2048, 256, 0, stream>>>(imgS, gpsS, i2g, g2i);
  ce_kernel<<<256, 256, 0, stream>>>(i2g, g2i, lsp, partial);
  finish_kernel<<<1, 256, 0, stream>>>(partial, out);
}